// Round 11
// baseline (6384.089 us; speedup 1.0000x reference)
//
#include <hip/hip_runtime.h>
#include <hip/hip_bf16.h>
#include <stdint.h>

// ---------- types ----------
typedef __attribute__((ext_vector_type(4))) float  f32x4;
typedef __attribute__((ext_vector_type(8))) short  bf16x8;
typedef __attribute__((ext_vector_type(8))) unsigned short u16x8;

#define MFMA16(d, x, y) d = __builtin_amdgcn_mfma_f32_16x16x32_bf16(x, y, d, 0, 0, 0)

// round f32 -> bf16 bits (RNE)
static __device__ inline unsigned short f2bf(float f) {
    union { float f; unsigned u; } a; a.f = f;
    unsigned u = a.u;
    unsigned lsb = (u >> 16) & 1u;
    u += 0x7fffu + lsb;
    return (unsigned short)(u >> 16);
}

// Emulate reference fp8_e4m3_round for positive x (x >= 1e-12).
static __device__ inline float fp8_e4m3_round(float x) {
    union { float f; unsigned u; } a; a.f = x;
    int e = (int)((a.u >> 23) & 255u) - 127;   // floor(log2(x)) exactly
    e = e < -6 ? -6 : (e > 8 ? 8 : e);
    union { unsigned u; float f; } stp, inv;
    stp.u = (unsigned)(e - 3 + 127) << 23;     // 2^(e-3)
    inv.u = (unsigned)(3 - e + 127) << 23;     // 2^(3-e)
    float r = rintf(x * inv.f) * stp.f;        // round-half-even == jnp.round
    return fminf(r, 448.0f);
}

// fp4 e2m1 level by strict midpoint comparison
static __device__ inline float fp4_level(float a) {
    return a > 2.5f ? (a > 3.5f ? (a > 5.0f ? 6.0f : 4.0f) : 3.0f)
                    : (a > 1.25f ? (a > 1.75f ? 2.0f : 1.5f)
                                 : (a > 0.75f ? 1.0f : (a > 0.25f ? 0.5f : 0.0f)));
}

// ---------- kernel 1: fused pre-pass (quant+deq X, deq W) ----------
__global__ void pre_kernel(const float* __restrict__ x, unsigned short* __restrict__ xd, int nblkx,
                           const float* __restrict__ wq, const float* __restrict__ wsc,
                           unsigned short* __restrict__ wd, int nblkw) {
    int i = blockIdx.x * blockDim.x + threadIdx.x;
    if (i < nblkx) {
        const float4* p = (const float4*)(x + (size_t)i * 16);
        float4 v0 = p[0], v1 = p[1], v2 = p[2], v3 = p[3];
        float vals[16] = { v0.x,v0.y,v0.z,v0.w, v1.x,v1.y,v1.z,v1.w,
                           v2.x,v2.y,v2.z,v2.w, v3.x,v3.y,v3.z,v3.w };
        float amax = 0.0f;
#pragma unroll
        for (int j = 0; j < 16; ++j) amax = fmaxf(amax, fabsf(vals[j]));
        float s0 = fmaxf(amax / 6.0f, 1e-12f);
        float s  = fmaxf(fp8_e4m3_round(s0), 1.0f / 512.0f);  // FP8_MIN = 2^-9
        u16x8 o0, o1;
#pragma unroll
        for (int j = 0; j < 16; ++j) {
            float v = vals[j] / s;
            float lev = fp4_level(fabsf(v));
            float q = copysignf(lev, v);
            unsigned short b = f2bf(q * s);
            if (j < 8) o0[j] = b; else o1[j - 8] = b;
        }
        u16x8* dst = (u16x8*)(xd + (size_t)i * 16);
        dst[0] = o0; dst[1] = o1;
    } else {
        int j = i - nblkx;
        if (j >= nblkw) return;
        float s = wsc[j];
        const float4* p = (const float4*)(wq + (size_t)j * 16);
        float4 v0 = p[0], v1 = p[1], v2 = p[2], v3 = p[3];
        float vals[16] = { v0.x,v0.y,v0.z,v0.w, v1.x,v1.y,v1.z,v1.w,
                           v2.x,v2.y,v2.z,v2.w, v3.x,v3.y,v3.z,v3.w };
        u16x8 o0, o1;
#pragma unroll
        for (int k = 0; k < 16; ++k) {
            unsigned short b = f2bf(vals[k] * s);
            if (k < 8) o0[k] = b; else o1[k - 8] = b;
        }
        u16x8* dst = (u16x8*)(wd + (size_t)j * 16);
        dst[0] = o0; dst[1] = o1;
    }
}

// ---------- kernel 2: 256x256x32 bf16 GEMM, 64KB LDS -> 2 WGs/CU ----------
// C[M][N] = A[M][K] * B[N][K]^T + bias.  8 waves (2Mx4N), per-wave 128x64.
// WHY: r7's 128KB LDS allowed only ONE WG/CU (Occupancy 23.5%) -> every
// barrier/vmcnt drain left the CU pipes idle.  BK=32 slices (NT=128) with
// 2 slice-buffers halve LDS to 64KB -> 2 WGs/CU co-resident; when one WG
// drains, the sibling's MFMAs fill the CU.  Per-WG phase shape is identical
// to r7 (4 gload_lds + 12 ds_reads + 32 MFMA + 1 barrier), so per-WG
// behavior is the validated one; the vmcnt ledger SIMPLIFIES:
//   phase t: [vmcnt(0): drains last phase's stage of tile t+1 (provable RAW);
//     bar; setprio1; stage tile t+2 -> buf t&1 (WAR: tile t's regs were read
//     in phase t-1; those ds_reads complete ~120cyc after pre-barrier issue,
//     staged writes land >=200cyc post-barrier -- r7-validated timing);
//     12 ds_reads tile t+1 -> regs (buf (t+1)&1); 32 MFMA tile t (regs from
//     last phase, compiler-counted lgkm); setprio0]
// LDS: A slices dbuf at 0/16384; B at 32768/49152.  st_16x32 swizzle both.
// No compiler-tracked vmem in the loop (only gload_lds).
static __device__ __forceinline__ void stage_half(const unsigned short* g0, const unsigned short* g1,
                                                  size_t koff, char* d0) {
    __builtin_amdgcn_global_load_lds((const __attribute__((address_space(1))) void*)(g0 + koff),
                                     (__attribute__((address_space(3))) void*)d0, 16, 0, 0);
    __builtin_amdgcn_global_load_lds((const __attribute__((address_space(1))) void*)(g1 + koff),
                                     (__attribute__((address_space(3))) void*)(d0 + 1024), 16, 0, 0);
}

#define MFMA_ALL(AV, BV) {                                              \
    _Pragma("unroll")                                                   \
    for (int mf = 0; mf < 8; ++mf) {                                    \
        _Pragma("unroll")                                               \
        for (int nf = 0; nf < 4; ++nf) MFMA16(acc[mf][nf], AV[mf], BV[nf]); } }

#define READ12(AV, BV, BUFOFF) {                                        \
    const char* _pa = lds + (BUFOFF) + wr * 8192 + lane_off;            \
    const char* _pb = lds + 32768 + (BUFOFF) + wc * 4096 + lane_off;    \
    _Pragma("unroll")                                                   \
    for (int i = 0; i < 8; ++i) AV[i] = *(const bf16x8*)(_pa + i * 1024); \
    _Pragma("unroll")                                                   \
    for (int i = 0; i < 4; ++i) BV[i] = *(const bf16x8*)(_pb + i * 1024); }

#define VMW(N) asm volatile("s_waitcnt vmcnt(" #N ")" ::: "memory")

// PHASE(t): compute tile T (ACUR/BCUR, read last phase); read T+1 -> ANXT/BNXT;
//           stage T+2 -> buf T&1
#define PHASE(T, ACUR, BCUR, ANXT, BNXT) {                              \
    VMW(0);                                                             \
    __builtin_amdgcn_s_barrier();                                       \
    __builtin_amdgcn_s_setprio(1);                                      \
    stage_half(gA0, gA1, (size_t)((T) + 2) * 32, ldsA_w + ((T) & 1) * 16384); \
    stage_half(gB0, gB1, (size_t)((T) + 2) * 32, ldsB_w + ((T) & 1) * 16384); \
    READ12(ANXT, BNXT, (((T) + 1) & 1) * 16384);                        \
    MFMA_ALL(ACUR, BCUR);                                               \
    __builtin_amdgcn_s_setprio(0); }

__global__ __launch_bounds__(512, 4)
void gemm_kernel(const unsigned short* __restrict__ A, const unsigned short* __restrict__ Bw,
                 const float* __restrict__ bias, float* __restrict__ C,
                 int M, int N, int K) {
    extern __shared__ char lds[];
    const int tid  = threadIdx.x;
    const int lane = tid & 63;
    const int wid  = tid >> 6;
    const int wr   = wid >> 2;       // 0..1
    const int wc   = wid & 3;        // 0..3

    const int NXB = N >> 8, NYB = M >> 8;
    int bid = blockIdx.x;
    int bx, by;
    if (NXB == 64 && NYB == 16) {    // XCD-aware swizzle (8 XCDs, 1024 wgs)
        int xcd = bid & 7, c = bid >> 3;
        bx = xcd * 8 + (c & 7);
        by = c >> 3;
    } else { bx = bid % NXB; by = bid / NXB; }

    const int NT = K >> 5;           // K-slices of 32 (K=4096 -> 128, even)

    // read-side swizzled lane offset within a 1024B subtile (st_16x32, 1 bit)
    int w0 = (lane & 15) * 64 + ((lane >> 4) << 4);
    const int lane_off = w0 ^ (((w0 >> 9) & 1) << 5);
    // write-side inverse permutation for staging: lane -> (row, col)
    const int u   = (lane * 16) ^ (lane & 32);   // bit9 of lane*16 == lane&32
    const int r_l = u >> 6;
    const int c_l = (u & 63) >> 1;

    const unsigned short* gA0 = A  + (size_t)(by * 256 + wid * 32 + r_l) * K + c_l;
    const unsigned short* gA1 = gA0 + (size_t)16 * K;
    const unsigned short* gB0 = Bw + (size_t)(bx * 256 + wid * 32 + r_l) * K + c_l;
    const unsigned short* gB1 = gB0 + (size_t)16 * K;
    char* ldsA_w = lds + wid * 2048 + lane * 16;           // + buf*16384
    char* ldsB_w = lds + 32768 + wid * 2048 + lane * 16;   // + buf*16384

    f32x4 acc[8][4];
#pragma unroll
    for (int m = 0; m < 8; ++m)
#pragma unroll
        for (int n = 0; n < 4; ++n)
#pragma unroll
            for (int j = 0; j < 4; ++j) acc[m][n][j] = 0.0f;

    bf16x8 a1[8], a2[8], b1[4], b2[4];

    // ---- prologue: stage tile0 -> buf0, tile1 -> buf1; read tile0 ----
    stage_half(gA0, gA1, 0,  ldsA_w);
    stage_half(gB0, gB1, 0,  ldsB_w);
    stage_half(gA0, gA1, 32, ldsA_w + 16384);
    stage_half(gB0, gB1, 32, ldsB_w + 16384);
    VMW(4);                                            // tile0 landed
    __builtin_amdgcn_s_barrier();
    READ12(a1, b1, 0);

    // ---- main loop: phases 0..NT-3 (each stages t+2, reads t+1, computes t)
    for (int t = 0; t <= NT - 4; t += 2) {
        PHASE(t,     a1, b1, a2, b2);
        PHASE(t + 1, a2, b2, a1, b1);
    }

    // ---- phase NT-2: read tile NT-1 (buf 1), compute NT-2; no stage ----
    {
        VMW(0);
        __builtin_amdgcn_s_barrier();
        READ12(a2, b2, 16384);                         // tile NT-1 (odd -> buf1)
        MFMA_ALL(a1, b1);
    }
    // ---- phase NT-1: compute tile NT-1 (lgkm counted by compiler) ----
    MFMA_ALL(a2, b2);

    // ---- C write: col = lane&15, row = (lane>>4)*4 + j ----
    const int row0 = by * 256 + wr * 128;
    const int col0 = bx * 256 + wc * 64;
#pragma unroll
    for (int nf = 0; nf < 4; ++nf) {
        int col = col0 + nf * 16 + (lane & 15);
        float bv = bias[col];
#pragma unroll
        for (int mf = 0; mf < 8; ++mf) {
#pragma unroll
            for (int j = 0; j < 4; ++j) {
                int row = row0 + mf * 16 + ((lane >> 4) << 2) + j;
                C[(size_t)row * N + col] = acc[mf][nf][j] + bv;
            }
        }
    }
}

// ---------- host ----------
extern "C" void kernel_launch(void* const* d_in, const int* in_sizes, int n_in,
                              void* d_out, int out_size, void* d_ws, size_t ws_size,
                              hipStream_t stream) {
    const float* x    = (const float*)d_in[0];
    const float* wq   = (const float*)d_in[1];
    const float* wsc  = (const float*)d_in[2];
    const float* bias = (const float*)d_in[3];
    float* out = (float*)d_out;

    const long N = in_sizes[3];                 // 16384
    const long K = (long)in_sizes[1] / N;       // 4096
    const long M = (long)in_sizes[0] / K;       // 4096

    size_t need = ((size_t)(M * K) + (size_t)(N * K)) * sizeof(unsigned short);
    if (ws_size < need) return;

    unsigned short* xd = (unsigned short*)d_ws;          // [M][K] bf16
    unsigned short* wd = xd + (size_t)M * K;             // [N][K] bf16

    {
        int nblkx = (int)(M * K / 16);
        int nblkw = (int)(N * K / 16);
        int total = nblkx + nblkw;
        pre_kernel<<<(total + 255) / 256, 256, 0, stream>>>(x, xd, nblkx, wq, wsc, wd, nblkw);
    }
    {
        hipFuncSetAttribute((const void*)gemm_kernel,
                            hipFuncAttributeMaxDynamicSharedMemorySize, 65536);
        int nwg = (int)((M / 256) * (N / 256));
        gemm_kernel<<<dim3(nwg), dim3(512), 65536, stream>>>(xd, wd, bias, out,
                                                             (int)M, (int)N, (int)K);
    }
}

// Round 12
// 550.254 us; speedup vs baseline: 11.6021x; 11.6021x over previous
//
#include <hip/hip_runtime.h>
#include <hip/hip_bf16.h>
#include <stdint.h>

// ---------- types ----------
typedef __attribute__((ext_vector_type(4))) float  f32x4;
typedef __attribute__((ext_vector_type(8))) short  bf16x8;
typedef __attribute__((ext_vector_type(8))) unsigned short u16x8;

#define MFMA16(d, x, y) d = __builtin_amdgcn_mfma_f32_16x16x32_bf16(x, y, d, 0, 0, 0)

// round f32 -> bf16 bits (RNE)
static __device__ inline unsigned short f2bf(float f) {
    union { float f; unsigned u; } a; a.f = f;
    unsigned u = a.u;
    unsigned lsb = (u >> 16) & 1u;
    u += 0x7fffu + lsb;
    return (unsigned short)(u >> 16);
}

// Emulate reference fp8_e4m3_round for positive x (x >= 1e-12).
static __device__ inline float fp8_e4m3_round(float x) {
    union { float f; unsigned u; } a; a.f = x;
    int e = (int)((a.u >> 23) & 255u) - 127;   // floor(log2(x)) exactly
    e = e < -6 ? -6 : (e > 8 ? 8 : e);
    union { unsigned u; float f; } stp, inv;
    stp.u = (unsigned)(e - 3 + 127) << 23;     // 2^(e-3)
    inv.u = (unsigned)(3 - e + 127) << 23;     // 2^(3-e)
    float r = rintf(x * inv.f) * stp.f;        // round-half-even == jnp.round
    return fminf(r, 448.0f);
}

// fp4 e2m1 level by strict midpoint comparison
static __device__ inline float fp4_level(float a) {
    return a > 2.5f ? (a > 3.5f ? (a > 5.0f ? 6.0f : 4.0f) : 3.0f)
                    : (a > 1.25f ? (a > 1.75f ? 2.0f : 1.5f)
                                 : (a > 0.75f ? 1.0f : (a > 0.25f ? 0.5f : 0.0f)));
}

// ---------- kernel 1: fused pre-pass (quant+deq X, deq W), grid-stride ------
__global__ void pre_kernel(const float* __restrict__ x, unsigned short* __restrict__ xd, int nblkx,
                           const float* __restrict__ wq, const float* __restrict__ wsc,
                           unsigned short* __restrict__ wd, int nblkw) {
    const int stride = gridDim.x * blockDim.x;
    const int total  = nblkx + nblkw;
    for (int i = blockIdx.x * blockDim.x + threadIdx.x; i < total; i += stride) {
        if (i < nblkx) {
            const float4* p = (const float4*)(x + (size_t)i * 16);
            float4 v0 = p[0], v1 = p[1], v2 = p[2], v3 = p[3];
            float vals[16] = { v0.x,v0.y,v0.z,v0.w, v1.x,v1.y,v1.z,v1.w,
                               v2.x,v2.y,v2.z,v2.w, v3.x,v3.y,v3.z,v3.w };
            float amax = 0.0f;
#pragma unroll
            for (int j = 0; j < 16; ++j) amax = fmaxf(amax, fabsf(vals[j]));
            float s0 = fmaxf(amax / 6.0f, 1e-12f);
            float s  = fmaxf(fp8_e4m3_round(s0), 1.0f / 512.0f);  // FP8_MIN = 2^-9
            u16x8 o0, o1;
#pragma unroll
            for (int j = 0; j < 16; ++j) {
                float v = vals[j] / s;
                float lev = fp4_level(fabsf(v));
                float q = copysignf(lev, v);
                unsigned short b = f2bf(q * s);
                if (j < 8) o0[j] = b; else o1[j - 8] = b;
            }
            u16x8* dst = (u16x8*)(xd + (size_t)i * 16);
            dst[0] = o0; dst[1] = o1;
        } else {
            int j = i - nblkx;
            float s = wsc[j];
            const float4* p = (const float4*)(wq + (size_t)j * 16);
            float4 v0 = p[0], v1 = p[1], v2 = p[2], v3 = p[3];
            float vals[16] = { v0.x,v0.y,v0.z,v0.w, v1.x,v1.y,v1.z,v1.w,
                               v2.x,v2.y,v2.z,v2.w, v3.x,v3.y,v3.z,v3.w };
            u16x8 o0, o1;
#pragma unroll
            for (int k = 0; k < 16; ++k) {
                unsigned short b = f2bf(vals[k] * s);
                if (k < 8) o0[k] = b; else o1[k - 8] = b;
            }
            u16x8* dst = (u16x8*)(wd + (size_t)j * 16);
            dst[0] = o0; dst[1] = o1;
        }
    }
}

// ---------- kernel 2: 256x256x64 bf16 GEMM (round-7 keeper, verbatim) -------
// C[M][N] = A[M][K] * B[N][K]^T + bias.  8 waves (2Mx4N), per-wave 128x64.
// LDS (128KB): A dbuf at 0/32768 (k0 @+0, k1 @+16384, st_16x32-swizzled
// 1024B subtiles); B same at 65536.
// Phase (one per k-slice, ONE barrier each):
//   [vmcnt(4); bar; setprio1; 12 ds_reads (NEXT slice) -> regs;
//    2 stage_half (future tiles); 32 MFMA (CURRENT slice, regs read last
//    phase, compiler-COUNTED lgkm waits -> LDS pipe overlaps MFMA); setprio0]
// Ledger:
//   RAW: every read is 1 phase after its stage; vmcnt(4) at phase start keeps
//        last phase's 4 stage-loads, drains the 2-phases-old stage;
//        gate+barrier precede the reads for ALL waves.
//   WAR: region overwritten by a stage was last read one phase earlier; those
//        reads lgkm-drain before that phase's MFMA, >=1 barrier before stage.
// No compiler-tracked vmem in the loop (only gload_lds) -> manual vmcnt
// doesn't fight the compiler's waitcnt pass (round-6 lesson).
// NOTE (measured fence, rounds 8-11): drain-per-phase (-13%), SGB interleave
// (-28%), B-from-global (-2.3x), 2-WG occupancy (reg-infeasible: 8-wave WG
// at 256 regs/wave fills the file).  This structure is the local optimum.
static __device__ __forceinline__ void stage_half(const unsigned short* g0, const unsigned short* g1,
                                                  size_t koff, char* d0) {
    __builtin_amdgcn_global_load_lds((const __attribute__((address_space(1))) void*)(g0 + koff),
                                     (__attribute__((address_space(3))) void*)d0, 16, 0, 0);
    __builtin_amdgcn_global_load_lds((const __attribute__((address_space(1))) void*)(g1 + koff),
                                     (__attribute__((address_space(3))) void*)(d0 + 1024), 16, 0, 0);
}

#define MFMA_ALL(AV, BV) {                                              \
    _Pragma("unroll")                                                   \
    for (int mf = 0; mf < 8; ++mf) {                                    \
        _Pragma("unroll")                                               \
        for (int nf = 0; nf < 4; ++nf) MFMA16(acc[mf][nf], AV[mf], BV[nf]); } }

#define READ12(AV, BV, OFF) {                                           \
    const char* _pa = lds + (OFF) + wr * 8192 + lane_off;               \
    const char* _pb = lds + 65536 + (OFF) + wc * 4096 + lane_off;       \
    _Pragma("unroll")                                                   \
    for (int i = 0; i < 8; ++i) AV[i] = *(const bf16x8*)(_pa + i * 1024); \
    _Pragma("unroll")                                                   \
    for (int i = 0; i < 4; ++i) BV[i] = *(const bf16x8*)(_pb + i * 1024); }

// H1(t): MFMA k0[t] (a1,b1); read k1[t] -> a2,b2; stage k1[t+1] -> buf b^1
#define PH1(T, B) {                                                     \
    asm volatile("s_waitcnt vmcnt(4)" ::: "memory");                    \
    __builtin_amdgcn_s_barrier();                                       \
    __builtin_amdgcn_s_setprio(1);                                      \
    READ12(a2, b2, (B) * 32768 + 16384);                                \
    stage_half(gA0, gA1, (size_t)((T) + 1) * 64 + 32, ldsA_w + (1 - (B)) * 32768 + 16384); \
    stage_half(gB0, gB1, (size_t)((T) + 1) * 64 + 32, ldsB_w + (1 - (B)) * 32768 + 16384); \
    MFMA_ALL(a1, b1);                                                   \
    __builtin_amdgcn_s_setprio(0); }

// H2(t): MFMA k1[t] (a2,b2); read k0[t+1] -> a1,b1; stage k0[t+2] -> buf b
#define PH2(T, B) {                                                     \
    asm volatile("s_waitcnt vmcnt(4)" ::: "memory");                    \
    __builtin_amdgcn_s_barrier();                                       \
    __builtin_amdgcn_s_setprio(1);                                      \
    READ12(a1, b1, (1 - (B)) * 32768);                                  \
    stage_half(gA0, gA1, (size_t)((T) + 2) * 64, ldsA_w + (B) * 32768); \
    stage_half(gB0, gB1, (size_t)((T) + 2) * 64, ldsB_w + (B) * 32768); \
    MFMA_ALL(a2, b2);                                                   \
    __builtin_amdgcn_s_setprio(0); }

__global__ __launch_bounds__(512, 2)
void gemm_kernel(const unsigned short* __restrict__ A, const unsigned short* __restrict__ Bw,
                 const float* __restrict__ bias, float* __restrict__ C,
                 int M, int N, int K) {
    extern __shared__ char lds[];
    const int tid  = threadIdx.x;
    const int lane = tid & 63;
    const int wid  = tid >> 6;
    const int wr   = wid >> 2;       // 0..1
    const int wc   = wid & 3;        // 0..3

    const int NXB = N >> 8, NYB = M >> 8;
    int bid = blockIdx.x;
    int bx, by;
    if (NXB == 64 && NYB == 16) {    // XCD-aware swizzle (8 XCDs, 1024 wgs)
        int xcd = bid & 7, c = bid >> 3;
        bx = xcd * 8 + (c & 7);
        by = c >> 3;
    } else { bx = bid % NXB; by = bid / NXB; }

    const int NT = K >> 6;           // K-tiles of 64 (K=4096 -> 64, even)

    // read-side swizzled lane offset within a 1024B subtile (st_16x32, 1 bit)
    int w0 = (lane & 15) * 64 + ((lane >> 4) << 4);
    const int lane_off = w0 ^ (((w0 >> 9) & 1) << 5);
    // write-side inverse permutation for staging: lane -> (row, col)
    const int u   = (lane * 16) ^ (lane & 32);   // bit9 of lane*16 == lane&32
    const int r_l = u >> 6;
    const int c_l = (u & 63) >> 1;

    const unsigned short* gA0 = A  + (size_t)(by * 256 + wid * 32 + r_l) * K + c_l;
    const unsigned short* gA1 = gA0 + (size_t)16 * K;
    const unsigned short* gB0 = Bw + (size_t)(bx * 256 + wid * 32 + r_l) * K + c_l;
    const unsigned short* gB1 = gB0 + (size_t)16 * K;
    char* ldsA_w = lds + wid * 2048 + lane * 16;           // + buf*32768 + s*16384
    char* ldsB_w = lds + 65536 + wid * 2048 + lane * 16;

    f32x4 acc[8][4];
#pragma unroll
    for (int m = 0; m < 8; ++m)
#pragma unroll
        for (int n = 0; n < 4; ++n)
#pragma unroll
            for (int j = 0; j < 4; ++j) acc[m][n][j] = 0.0f;

    bf16x8 a1[8], a2[8], b1[4], b2[4];

    // ---- prologue: stage t0k0, t0k1, t1k0 (12 loads); read t0k0 ----
    stage_half(gA0, gA1, 0,  ldsA_w);
    stage_half(gB0, gB1, 0,  ldsB_w);
    stage_half(gA0, gA1, 32, ldsA_w + 16384);
    stage_half(gB0, gB1, 32, ldsB_w + 16384);
    stage_half(gA0, gA1, 64, ldsA_w + 32768);
    stage_half(gB0, gB1, 64, ldsB_w + 32768);
    asm volatile("s_waitcnt vmcnt(8)" ::: "memory");   // t0k0 (A+B) landed
    __builtin_amdgcn_s_barrier();
    READ12(a1, b1, 0);

    // ---- main loop: tiles 0..NT-3, two K-tiles per iteration ----
    for (int t = 0; t <= NT - 4; t += 2) {
        PH1(t, 0);  PH2(t, 0);
        PH1(t + 1, 1);  PH2(t + 1, 1);
    }

    // ---- tile NT-2 (buf 0): normal H1; H2 without stage ----
    PH1(NT - 2, 0);
    {
        asm volatile("s_waitcnt vmcnt(4)" ::: "memory");   // drains k0[NT-1]
        __builtin_amdgcn_s_barrier();
        READ12(a1, b1, 32768);                             // k0[NT-1], buf 1
        MFMA_ALL(a2, b2);
    }
    // ---- tile NT-1 (buf 1): H1 with vmcnt(0); final MFMA, no barrier ----
    {
        asm volatile("s_waitcnt vmcnt(0)" ::: "memory");   // drains k1[NT-1]
        __builtin_amdgcn_s_barrier();
        READ12(a2, b2, 32768 + 16384);                     // k1[NT-1]
        MFMA_ALL(a1, b1);
        MFMA_ALL(a2, b2);
    }

    // ---- C write: col = lane&15, row = (lane>>4)*4 + j ----
    const int row0 = by * 256 + wr * 128;
    const int col0 = bx * 256 + wc * 64;
#pragma unroll
    for (int nf = 0; nf < 4; ++nf) {
        int col = col0 + nf * 16 + (lane & 15);
        float bv = bias[col];
#pragma unroll
        for (int mf = 0; mf < 8; ++mf) {
#pragma unroll
            for (int j = 0; j < 4; ++j) {
                int row = row0 + mf * 16 + ((lane >> 4) << 2) + j;
                C[(size_t)row * N + col] = acc[mf][nf][j] + bv;
            }
        }
    }
}

// ---------- host ----------
extern "C" void kernel_launch(void* const* d_in, const int* in_sizes, int n_in,
                              void* d_out, int out_size, void* d_ws, size_t ws_size,
                              hipStream_t stream) {
    const float* x    = (const float*)d_in[0];
    const float* wq   = (const float*)d_in[1];
    const float* wsc  = (const float*)d_in[2];
    const float* bias = (const float*)d_in[3];
    float* out = (float*)d_out;

    const long N = in_sizes[3];                 // 16384
    const long K = (long)in_sizes[1] / N;       // 4096
    const long M = (long)in_sizes[0] / K;       // 4096

    size_t need = ((size_t)(M * K) + (size_t)(N * K)) * sizeof(unsigned short);
    if (ws_size < need) return;

    unsigned short* xd = (unsigned short*)d_ws;          // [M][K] bf16
    unsigned short* wd = xd + (size_t)M * K;             // [N][K] bf16

    {
        int nblkx = (int)(M * K / 16);
        int nblkw = (int)(N * K / 16);
        pre_kernel<<<2048, 256, 0, stream>>>(x, xd, nblkx, wq, wsc, wd, nblkw);
    }
    {
        hipFuncSetAttribute((const void*)gemm_kernel,
                            hipFuncAttributeMaxDynamicSharedMemorySize, 131072);
        int nwg = (int)((M / 256) * (N / 256));
        gemm_kernel<<<dim3(nwg), dim3(512), 131072, stream>>>(xd, wd, bias, out,
                                                              (int)M, (int)N, (int)K);
    }
}